// Round 7
// baseline (4327.118 us; speedup 1.0000x reference)
//
#include <hip/hip_runtime.h>
#include <math.h>

#define B_ROWS 262144
#define GAMMA_C 1.3f
#define EPS_C 1e-5f
#define SQH_C 0.70710678118654752440f
#define SL_SCALE (1.0f/201326592.0f)   // 1/(3*B*256)

typedef _Float16 f16;
typedef f16 f16x8 __attribute__((ext_vector_type(8)));
typedef f16 f16x4 __attribute__((ext_vector_type(4)));
typedef float f32x4 __attribute__((ext_vector_type(4)));

// LDS pool layout (bytes)
#define OFF_SZ  32768    // att z-buffer 64KB (32768..98304); att sW = 32KB at 0
#define OFF_SO  98304    // 16KB transpose buf (inside 64..128K; K=128 sW uses 0..64K)
#define OFF_SA  131072   // 16KB A staging
#define OFF_S1  147456   // float[512]
#define OFF_S2  149504   // float[512]
#define OFF_AF  151552   // float[256]
#define OFF_BF  152576   // float[256]
#define OFF_BA  153600   // float[256] bn0 scale
#define OFF_BB  154624   // float[256] bn0 offset
#define OFF_M0  155648   // float[256]
#define OFF_P0  156672   // float[256]
#define OFF_ENT 157696   // float[16]
#define SMEM_SZ 157760

__device__ __forceinline__ int SWZ(int row, int kb, int RB, int MSK) {
  return row * RB + (kb ^ ((row & MSK) << 4));
}

// ---------------- bn0 ----------------
__global__ void bn0_accum(const float* __restrict__ x, float* __restrict__ sums) {
  const int col = threadIdx.x;
  const size_t r0 = (size_t)blockIdx.x * 128;
  float s1 = 0.f, s2 = 0.f;
  for (int i = 0; i < 128; ++i) {
    float v = x[(r0 + i) * 256 + col];
    s1 += v; s2 += v * v;
  }
  atomicAdd(&sums[col * 2], s1);
  atomicAdd(&sums[col * 2 + 1], s2);
}

__global__ void bn0_final(const float* __restrict__ sums, const float* __restrict__ g,
                          const float* __restrict__ b, float* __restrict__ bnA,
                          float* __restrict__ bnB) {
  int c = threadIdx.x;
  float mu = sums[c * 2] * (1.f / B_ROWS);
  float var = sums[c * 2 + 1] * (1.f / B_ROWS) - mu * mu;
  float a = rsqrtf(var + EPS_C) * g[c];
  bnA[c] = a;
  bnB[c] = b[c] - mu * a;
}

// ---------------- weight prep: f32 [K][256] -> f16 [256][K] ----------------
__global__ void wprep(const float* __restrict__ src, f16* __restrict__ dst, int K) {
  int idx = blockIdx.x * 256 + threadIdx.x;
  int n = idx / K, k = idx - n * K;
  dst[idx] = (f16)src[(size_t)k * 256 + n];
}

// ---------------- K=256 GLU (sh0): Mx(global) -> h0 (global f16) ----------------
__device__ __forceinline__ void glu256_phase(
    char* __restrict__ P, const int tid, const int r0,
    const f16* __restrict__ Wt, const float* __restrict__ gv, const float* __restrict__ bv,
    const f16* __restrict__ MxG, f16* __restrict__ h0G)
{
  const int w = tid >> 6, l = tid & 63, lg = l >> 4, lc = l & 15;
  const int mw = w >> 3, nw = w & 7;
  char* sW = P;
  char* sA = P + OFF_SA;
  float* sS1 = (float*)(P + OFF_S1);
  float* sS2 = (float*)(P + OFF_S2);
  float* sAf = (float*)(P + OFF_AF);
  float* sBf = (float*)(P + OFF_BF);
  const int c1 = nw * 16 + lc, c2 = c1 + 128;

  __syncthreads();
#pragma unroll
  for (int it = 0; it < 8; ++it) {            // stage W: 256 n x 256 k
    int slot = it * 1024 + tid;
    int n = slot >> 5, kc = slot & 31;
    *(f16x8*)(sW + SWZ(n, kc * 16, 512, 31)) = *(const f16x8*)(Wt + n * 256 + kc * 8);
  }
  float st1a = 0.f, st2a = 0.f, st1b = 0.f, st2b = 0.f;
  for (int ch = 0; ch < 32; ++ch) {           // pass 0: stats
    __syncthreads();
    {
      int row = tid >> 5, kc = tid & 31;
      *(f16x8*)(sA + SWZ(row, kc * 16, 512, 31)) =
          *(const f16x8*)(MxG + (size_t)(r0 + ch * 32 + row) * 256 + kc * 8);
    }
    __syncthreads();
    f32x4 a0 = {0.f,0.f,0.f,0.f}, a1 = {0.f,0.f,0.f,0.f};
#pragma unroll
    for (int ks = 0; ks < 8; ++ks) {
      f16x8 af = *(const f16x8*)(sA + SWZ(mw * 16 + lc, ks * 64 + lg * 16, 512, 31));
      f16x8 b0 = *(const f16x8*)(sW + SWZ(nw * 16 + lc, ks * 64 + lg * 16, 512, 31));
      f16x8 b1 = *(const f16x8*)(sW + SWZ((nw + 8) * 16 + lc, ks * 64 + lg * 16, 512, 31));
      a0 = __builtin_amdgcn_mfma_f32_16x16x32_f16(af, b0, a0, 0, 0, 0);
      a1 = __builtin_amdgcn_mfma_f32_16x16x32_f16(af, b1, a1, 0, 0, 0);
    }
#pragma unroll
    for (int j = 0; j < 4; ++j) {
      st1a += a0[j]; st2a += a0[j] * a0[j];
      st1b += a1[j]; st2b += a1[j] * a1[j];
    }
  }
  st1a += __shfl_xor(st1a, 16); st1a += __shfl_xor(st1a, 32);
  st2a += __shfl_xor(st2a, 16); st2a += __shfl_xor(st2a, 32);
  st1b += __shfl_xor(st1b, 16); st1b += __shfl_xor(st1b, 32);
  st2b += __shfl_xor(st2b, 16); st2b += __shfl_xor(st2b, 32);
  if (l < 16) {
    sS1[mw * 256 + c1] = st1a; sS2[mw * 256 + c1] = st2a;
    sS1[mw * 256 + c2] = st1b; sS2[mw * 256 + c2] = st2b;
  }
  __syncthreads();
  if (tid < 256) {
    float s1 = sS1[tid] + sS1[256 + tid];
    float s2 = sS2[tid] + sS2[256 + tid];
    float mu = s1 * (1.f / 1024.f);
    float var = s2 * (1.f / 1024.f) - mu * mu;
    float a = rsqrtf(var + EPS_C) * gv[tid];
    sAf[tid] = a; sBf[tid] = bv[tid] - mu * a;
  }
  __syncthreads();
  const float bA1 = sAf[c1], bO1 = sBf[c1], bA2 = sAf[c2], bO2 = sBf[c2];
  for (int ch = 0; ch < 32; ++ch) {           // pass 1: apply, write h0 global
    __syncthreads();
    {
      int row = tid >> 5, kc = tid & 31;
      *(f16x8*)(sA + SWZ(row, kc * 16, 512, 31)) =
          *(const f16x8*)(MxG + (size_t)(r0 + ch * 32 + row) * 256 + kc * 8);
    }
    __syncthreads();
    f32x4 a0 = {0.f,0.f,0.f,0.f}, a1 = {0.f,0.f,0.f,0.f};
#pragma unroll
    for (int ks = 0; ks < 8; ++ks) {
      f16x8 af = *(const f16x8*)(sA + SWZ(mw * 16 + lc, ks * 64 + lg * 16, 512, 31));
      f16x8 b0 = *(const f16x8*)(sW + SWZ(nw * 16 + lc, ks * 64 + lg * 16, 512, 31));
      f16x8 b1 = *(const f16x8*)(sW + SWZ((nw + 8) * 16 + lc, ks * 64 + lg * 16, 512, 31));
      a0 = __builtin_amdgcn_mfma_f32_16x16x32_f16(af, b0, a0, 0, 0, 0);
      a1 = __builtin_amdgcn_mfma_f32_16x16x32_f16(af, b1, a1, 0, 0, 0);
    }
#pragma unroll
    for (int j = 0; j < 4; ++j) {
      float g1 = a0[j] * bA1 + bO1;
      float g2 = a1[j] * bA2 + bO2;
      float hv = g1 / (1.f + __expf(-g2));
      h0G[(size_t)(r0 + ch * 32 + mw * 16 + lg * 4 + j) * 128 + c1] = (f16)hv;
    }
  }
}

// ---------------- K=128 GLU: A = h0G (SRC 0) or h regs (SRC 1); resid; opt dout ----------------
template <int SRC, int DOUT>
__device__ __forceinline__ void glu128_phase(
    char* __restrict__ P, const int tid, const int r0, const int s,
    const f16* __restrict__ Wt, const float* __restrict__ gv, const float* __restrict__ bv,
    const f16* __restrict__ h0G, float* __restrict__ dout, f16x8 (&h)[16])
{
  const int w = tid >> 6, l = tid & 63, lg = l >> 4, lc = l & 15;
  const int mw = w >> 3, nw = w & 7;
  char* sW = P;
  char* sO = P + OFF_SO;
  char* sA = P + OFF_SA;
  float* sS1 = (float*)(P + OFF_S1);
  float* sS2 = (float*)(P + OFF_S2);
  float* sAf = (float*)(P + OFF_AF);
  float* sBf = (float*)(P + OFF_BF);
  const int c1 = nw * 16 + lc, c2 = c1 + 128;

  __syncthreads();
#pragma unroll
  for (int it = 0; it < 4; ++it) {            // stage W: 256 n x 128 k
    int slot = it * 1024 + tid;
    int n = slot >> 4, kc = slot & 15;
    *(f16x8*)(sW + SWZ(n, kc * 16, 256, 15)) = *(const f16x8*)(Wt + n * 128 + kc * 8);
  }
  float st1a = 0.f, st2a = 0.f, st1b = 0.f, st2b = 0.f;
  for (int ch = 0; ch < 16; ++ch) {           // pass 0
    __syncthreads();
    if (SRC == 0) {
      int row = tid >> 4, kc = tid & 15;
      *(f16x8*)(sA + SWZ(row, kc * 16, 256, 15)) =
          *(const f16x8*)(h0G + (size_t)(r0 + ch * 64 + row) * 128 + kc * 8);
    } else {
      int idx = tid - ch * 64;
      if (idx >= 0 && idx < 64) {
#pragma unroll
        for (int t2 = 0; t2 < 16; ++t2)
          *(f16x8*)(sA + SWZ(idx, t2 * 16, 256, 15)) = h[t2];
      }
    }
    __syncthreads();
#pragma unroll
    for (int mt = 0; mt < 2; ++mt) {
      f32x4 a0 = {0.f,0.f,0.f,0.f}, a1 = {0.f,0.f,0.f,0.f};
      const int ar = (mw * 2 + mt) * 16 + lc;
#pragma unroll
      for (int ks = 0; ks < 4; ++ks) {
        f16x8 af = *(const f16x8*)(sA + SWZ(ar, ks * 64 + lg * 16, 256, 15));
        f16x8 b0 = *(const f16x8*)(sW + SWZ(nw * 16 + lc, ks * 64 + lg * 16, 256, 15));
        f16x8 b1 = *(const f16x8*)(sW + SWZ((nw + 8) * 16 + lc, ks * 64 + lg * 16, 256, 15));
        a0 = __builtin_amdgcn_mfma_f32_16x16x32_f16(af, b0, a0, 0, 0, 0);
        a1 = __builtin_amdgcn_mfma_f32_16x16x32_f16(af, b1, a1, 0, 0, 0);
      }
#pragma unroll
      for (int j = 0; j < 4; ++j) {
        st1a += a0[j]; st2a += a0[j] * a0[j];
        st1b += a1[j]; st2b += a1[j] * a1[j];
      }
    }
  }
  st1a += __shfl_xor(st1a, 16); st1a += __shfl_xor(st1a, 32);
  st2a += __shfl_xor(st2a, 16); st2a += __shfl_xor(st2a, 32);
  st1b += __shfl_xor(st1b, 16); st1b += __shfl_xor(st1b, 32);
  st2b += __shfl_xor(st2b, 16); st2b += __shfl_xor(st2b, 32);
  if (l < 16) {
    sS1[mw * 256 + c1] = st1a; sS2[mw * 256 + c1] = st2a;
    sS1[mw * 256 + c2] = st1b; sS2[mw * 256 + c2] = st2b;
  }
  __syncthreads();
  if (tid < 256) {
    float s1 = sS1[tid] + sS1[256 + tid];
    float s2 = sS2[tid] + sS2[256 + tid];
    float mu = s1 * (1.f / 1024.f);
    float var = s2 * (1.f / 1024.f) - mu * mu;
    float a = rsqrtf(var + EPS_C) * gv[tid];
    sAf[tid] = a; sBf[tid] = bv[tid] - mu * a;
  }
  __syncthreads();
  const float bA1 = sAf[c1], bO1 = sBf[c1], bA2 = sAf[c2], bO2 = sBf[c2];
  for (int ch = 0; ch < 16; ++ch) {           // pass 1
    __syncthreads();
    if (SRC == 0) {
      int row = tid >> 4, kc = tid & 15;
      *(f16x8*)(sA + SWZ(row, kc * 16, 256, 15)) =
          *(const f16x8*)(h0G + (size_t)(r0 + ch * 64 + row) * 128 + kc * 8);
    } else {
      int idx = tid - ch * 64;
      if (idx >= 0 && idx < 64) {
#pragma unroll
        for (int t2 = 0; t2 < 16; ++t2)
          *(f16x8*)(sA + SWZ(idx, t2 * 16, 256, 15)) = h[t2];
      }
    }
    __syncthreads();
#pragma unroll
    for (int mt = 0; mt < 2; ++mt) {
      f32x4 a0 = {0.f,0.f,0.f,0.f}, a1 = {0.f,0.f,0.f,0.f};
      const int ar = (mw * 2 + mt) * 16 + lc;
#pragma unroll
      for (int ks = 0; ks < 4; ++ks) {
        f16x8 af = *(const f16x8*)(sA + SWZ(ar, ks * 64 + lg * 16, 256, 15));
        f16x8 b0 = *(const f16x8*)(sW + SWZ(nw * 16 + lc, ks * 64 + lg * 16, 256, 15));
        f16x8 b1 = *(const f16x8*)(sW + SWZ((nw + 8) * 16 + lc, ks * 64 + lg * 16, 256, 15));
        a0 = __builtin_amdgcn_mfma_f32_16x16x32_f16(af, b0, a0, 0, 0, 0);
        a1 = __builtin_amdgcn_mfma_f32_16x16x32_f16(af, b1, a1, 0, 0, 0);
      }
#pragma unroll
      for (int j = 0; j < 4; ++j) {
        float g1 = a0[j] * bA1 + bO1;
        float g2 = a1[j] * bA2 + bO2;
        float hv = g1 / (1.f + __expf(-g2));
        const int rl = (mw * 2 + mt) * 16 + lg * 4 + j;
        f16 hp = *(const f16*)(sA + SWZ(rl, c1 * 2, 256, 15));   // A-tile IS h_prev
        hv = (hv + (float)hp) * SQH_C;
        if (DOUT && nw < 4) {
          float rv = fmaxf(hv, 0.f);
          float* dp = dout + (size_t)(r0 + ch * 64 + rl) * 64 + c1;
          if (s == 0) *dp = rv; else *dp += rv;
        }
        *(f16*)(sO + SWZ(rl, c1 * 2, 256, 15)) = (f16)hv;
      }
    }
    __syncthreads();
    {
      int idx = tid - ch * 64;
      if (idx >= 0 && idx < 64) {
#pragma unroll
        for (int t2 = 0; t2 < 16; ++t2)
          h[t2] = *(const f16x8*)(sO + SWZ(idx, t2 * 16, 256, 15));
      }
    }
  }
}

// ---------------- attention + ghost-BN + sparsemax + masks/Mx/P1 ----------------
template <int SMODE>   // 1: prior = sP0 vector, write P1; 2: prior from P1 buffer
__device__ __forceinline__ void att_phase(
    char* __restrict__ P, const int tid, const int r0,
    const f16* __restrict__ Wt, const float* __restrict__ ga, const float* __restrict__ ba,
    const float* __restrict__ x, f16* __restrict__ P1, f16* __restrict__ MxG,
    float* __restrict__ mkS, f16x8 (&h)[16], float& entAcc)
{
  const int w = tid >> 6, l = tid & 63, lg = l >> 4, lc = l & 15;
  const int mw = w >> 3, nw = w & 7;
  char* sW = P;
  char* sZ = P + OFF_SZ;
  char* sA = P + OFF_SA;
  float* sS1 = (float*)(P + OFF_S1);
  float* sS2 = (float*)(P + OFF_S2);
  float* sAf = (float*)(P + OFF_AF);
  float* sBf = (float*)(P + OFF_BF);
  float* sbA = (float*)(P + OFF_BA);
  float* sbB = (float*)(P + OFF_BB);
  float* sP0 = (float*)(P + OFF_P0);
  const int c1 = nw * 16 + lc, c2 = c1 + 128;

  __syncthreads();
#pragma unroll
  for (int it = 0; it < 2; ++it) {            // stage W_att: 256 n x 64 k
    int slot = it * 1024 + tid;
    int n = slot >> 3, kc = slot & 7;
    *(f16x8*)(sW + SWZ(n, kc * 16, 128, 7)) = *(const f16x8*)(Wt + n * 64 + kc * 8);
  }
  float st1a = 0.f, st2a = 0.f, st1b = 0.f, st2b = 0.f;
  for (int ch = 0; ch < 16; ++ch) {           // pass 0
    __syncthreads();
    {
      int idx = tid - ch * 64;
      if (idx >= 0 && idx < 64) {
#pragma unroll
        for (int t2 = 8; t2 < 16; ++t2)
          *(f16x8*)(sA + SWZ(idx, (t2 - 8) * 16, 128, 7)) = h[t2];
      }
    }
    __syncthreads();
#pragma unroll
    for (int mt = 0; mt < 2; ++mt) {
      f32x4 a0 = {0.f,0.f,0.f,0.f}, a1 = {0.f,0.f,0.f,0.f};
      const int ar = (mw * 2 + mt) * 16 + lc;
#pragma unroll
      for (int ks = 0; ks < 2; ++ks) {
        f16x8 af = *(const f16x8*)(sA + SWZ(ar, ks * 64 + lg * 16, 128, 7));
        f16x8 b0 = *(const f16x8*)(sW + SWZ(nw * 16 + lc, ks * 64 + lg * 16, 128, 7));
        f16x8 b1 = *(const f16x8*)(sW + SWZ((nw + 8) * 16 + lc, ks * 64 + lg * 16, 128, 7));
        a0 = __builtin_amdgcn_mfma_f32_16x16x32_f16(af, b0, a0, 0, 0, 0);
        a1 = __builtin_amdgcn_mfma_f32_16x16x32_f16(af, b1, a1, 0, 0, 0);
      }
#pragma unroll
      for (int j = 0; j < 4; ++j) {
        st1a += a0[j]; st2a += a0[j] * a0[j];
        st1b += a1[j]; st2b += a1[j] * a1[j];
      }
    }
  }
  st1a += __shfl_xor(st1a, 16); st1a += __shfl_xor(st1a, 32);
  st2a += __shfl_xor(st2a, 16); st2a += __shfl_xor(st2a, 32);
  st1b += __shfl_xor(st1b, 16); st1b += __shfl_xor(st1b, 32);
  st2b += __shfl_xor(st2b, 16); st2b += __shfl_xor(st2b, 32);
  if (l < 16) {
    sS1[mw * 256 + c1] = st1a; sS2[mw * 256 + c1] = st2a;
    sS1[mw * 256 + c2] = st1b; sS2[mw * 256 + c2] = st2b;
  }
  __syncthreads();
  if (tid < 256) {
    float s1 = sS1[tid] + sS1[256 + tid];
    float s2 = sS2[tid] + sS2[256 + tid];
    float mu = s1 * (1.f / 1024.f);
    float var = s2 * (1.f / 1024.f) - mu * mu;
    float a = rsqrtf(var + EPS_C) * ga[tid];
    sAf[tid] = a; sBf[tid] = ba[tid] - mu * a;
  }
  __syncthreads();
  const float aA1 = sAf[c1], aO1 = sBf[c1], aA2 = sAf[c2], aO2 = sBf[c2];
  float pv1 = 0.f, pv2 = 0.f;
  if (SMODE == 1) { pv1 = sP0[c1]; pv2 = sP0[c2]; }
  for (int ch = 0; ch < 16; ++ch) {           // pass 1
    __syncthreads();
    {
      int idx = tid - ch * 64;
      if (idx >= 0 && idx < 64) {
#pragma unroll
        for (int t2 = 8; t2 < 16; ++t2)
          *(f16x8*)(sA + SWZ(idx, (t2 - 8) * 16, 128, 7)) = h[t2];
      }
    }
    __syncthreads();
#pragma unroll
    for (int mt = 0; mt < 2; ++mt) {
      f32x4 a0 = {0.f,0.f,0.f,0.f}, a1 = {0.f,0.f,0.f,0.f};
      const int ar = (mw * 2 + mt) * 16 + lc;
#pragma unroll
      for (int ks = 0; ks < 2; ++ks) {
        f16x8 af = *(const f16x8*)(sA + SWZ(ar, ks * 64 + lg * 16, 128, 7));
        f16x8 b0 = *(const f16x8*)(sW + SWZ(nw * 16 + lc, ks * 64 + lg * 16, 128, 7));
        f16x8 b1 = *(const f16x8*)(sW + SWZ((nw + 8) * 16 + lc, ks * 64 + lg * 16, 128, 7));
        a0 = __builtin_amdgcn_mfma_f32_16x16x32_f16(af, b0, a0, 0, 0, 0);
        a1 = __builtin_amdgcn_mfma_f32_16x16x32_f16(af, b1, a1, 0, 0, 0);
      }
#pragma unroll
      for (int j = 0; j < 4; ++j) {
        const int rl = (mw * 2 + mt) * 16 + lg * 4 + j;
        const size_t rg = (size_t)(r0 + ch * 64 + rl);
        float z1 = a0[j] * aA1 + aO1;
        float z2 = a1[j] * aA2 + aO2;
        if (SMODE == 1) { z1 *= pv1; z2 *= pv2; }
        else {
          z1 *= (float)P1[rg * 256 + c1];
          z2 *= (float)P1[rg * 256 + c2];
        }
        *(float*)(sZ + rl * 1024 + ((c1 * 4) ^ ((rl & 31) << 4))) = z1;
        *(float*)(sZ + rl * 1024 + ((c2 * 4) ^ ((rl & 31) << 4))) = z2;
      }
    }
    __syncthreads();
    {
      const int rl = w * 4 + lg;               // 16 waves x 4 rows = 64 rows
      const size_t rg = (size_t)(r0 + ch * 64 + rl);
      f32x4 zz[4];
#pragma unroll
      for (int q = 0; q < 4; ++q)
        zz[q] = *(const f32x4*)(sZ + rl * 1024 + (((lc * 64) + q * 16) ^ ((rl & 31) << 4)));
      float m = zz[0][0];
#pragma unroll
      for (int q = 0; q < 4; ++q)
#pragma unroll
        for (int e = 0; e < 4; ++e) m = fmaxf(m, zz[q][e]);
#pragma unroll
      for (int d = 1; d < 16; d <<= 1) m = fmaxf(m, __shfl_xor(m, d));
      float lo = m - 1.f, hi = m;
      for (int it = 0; it < 20; ++it) {
        float tau = 0.5f * (lo + hi);
        float ss = 0.f;
#pragma unroll
        for (int q = 0; q < 4; ++q)
#pragma unroll
          for (int e = 0; e < 4; ++e) ss += fmaxf(zz[q][e] - tau, 0.f);
#pragma unroll
        for (int d = 1; d < 16; d <<= 1) ss += __shfl_xor(ss, d);
        if (ss > 1.f) lo = tau; else hi = tau;
      }
      const float tau = 0.5f * (lo + hi);
      f32x4 xv[4];
#pragma unroll
      for (int q = 0; q < 4; ++q) xv[q] = *(const f32x4*)(x + rg * 256 + lc * 16 + q * 4);
      float* mp = mkS + rg * 256 + lc * 16;
      f16x8 mxa, mxb, p1a, p1b;
      float entp = 0.f;
#pragma unroll
      for (int q = 0; q < 4; ++q) {
#pragma unroll
        for (int e = 0; e < 4; ++e) {
          const int k = q * 4 + e;
          const int c = lc * 16 + k;
          float M = fmaxf(zz[q][e] - tau, 0.f);
          mp[k] = M;
          entp -= M * __logf(M + 1e-15f);
          float mxv = M * (xv[q][e] * sbA[c] + sbB[c]);
          if (k < 8) mxa[k] = (f16)mxv; else mxb[k - 8] = (f16)mxv;
          if (SMODE == 1) {
            float pv = sP0[c] * (GAMMA_C - M);
            if (k < 8) p1a[k] = (f16)pv; else p1b[k - 8] = (f16)pv;
          }
        }
      }
      entAcc += entp;
      *(f16x8*)(MxG + rg * 256 + lc * 16) = mxa;
      *(f16x8*)(MxG + rg * 256 + lc * 16 + 8) = mxb;
      if (SMODE == 1) {
        *(f16x8*)(P1 + rg * 256 + lc * 16) = p1a;
        *(f16x8*)(P1 + rg * 256 + lc * 16 + 8) = p1b;
      }
    }
  }
}

// ---------------- mega kernel: one WG per VB, 1024 threads, all 3 steps ----------------
__global__ __launch_bounds__(1024) void mega(
    const float* __restrict__ x, const float* __restrict__ bnA, const float* __restrict__ bnB,
    const f16* __restrict__ wAtt, const f16* __restrict__ wSh0, const f16* __restrict__ wSh1,
    const f16* __restrict__ wSt,
    const float* __restrict__ gsh0, const float* __restrict__ bsh0,
    const float* __restrict__ gsh1, const float* __restrict__ bsh1,
    const float* __restrict__ gstep, const float* __restrict__ bstep,
    const float* __restrict__ gatt, const float* __restrict__ batt,
    f16* __restrict__ P1, f16* __restrict__ MxG, f16* __restrict__ h0G,
    float* __restrict__ masks, float* __restrict__ dout, float* __restrict__ slpart)
{
  __shared__ __align__(16) char P[SMEM_SZ];
  const int tid = threadIdx.x;
  const int w = tid >> 6, l = tid & 63;
  const int r0 = blockIdx.x << 10;
  float* sbA = (float*)(P + OFF_BA);
  float* sbB = (float*)(P + OFF_BB);
  float* sM0 = (float*)(P + OFF_M0);
  float* sP0 = (float*)(P + OFF_P0);
  float* sEnt = (float*)(P + OFF_ENT);
  f16x8 h[16];
  float entAcc = 0.f;
  if (tid < 256) { sbA[tid] = bnA[tid]; sbB[tid] = bnB[tid]; }

  for (int s = 0; s < 3; ++s) {
    float* mkS = masks + (size_t)s * B_ROWS * 256;
    if (s == 0) {
      if (w == 0) {        // step-0 mask = sparsemax(batt), one vector
        float z0 = batt[l * 4], z1 = batt[l * 4 + 1], z2 = batt[l * 4 + 2], z3 = batt[l * 4 + 3];
        float m = fmaxf(fmaxf(z0, z1), fmaxf(z2, z3));
#pragma unroll
        for (int d = 1; d < 64; d <<= 1) m = fmaxf(m, __shfl_xor(m, d));
        float lo = m - 1.f, hi = m;
        for (int it = 0; it < 24; ++it) {
          float tau = 0.5f * (lo + hi);
          float ss = fmaxf(z0 - tau, 0.f) + fmaxf(z1 - tau, 0.f) +
                     fmaxf(z2 - tau, 0.f) + fmaxf(z3 - tau, 0.f);
#pragma unroll
          for (int d = 1; d < 64; d <<= 1) ss += __shfl_xor(ss, d);
          if (ss > 1.f) lo = tau; else hi = tau;
        }
        float tau = 0.5f * (lo + hi);
        float zz[4] = {z0, z1, z2, z3};
        float entp = 0.f;
#pragma unroll
        for (int e = 0; e < 4; ++e) {
          float M = fmaxf(zz[e] - tau, 0.f);
          sM0[l * 4 + e] = M;
          sP0[l * 4 + e] = GAMMA_C - M;
          entp -= M * __logf(M + 1e-15f);
        }
        entAcc += 1024.f * entp;
      }
      __syncthreads();
      float M0v[4], bA0[4], bB0[4];
#pragma unroll
      for (int e = 0; e < 4; ++e) {
        M0v[e] = sM0[l * 4 + e];
        bA0[e] = sbA[l * 4 + e];
        bB0[e] = sbB[l * 4 + e];
      }
      for (int rr = 0; rr < 64; ++rr) {
        const size_t rg = (size_t)(r0 + w * 64 + rr);
        f32x4 xv = *(const f32x4*)(x + rg * 256 + l * 4);
        float* mp = mkS + rg * 256 + l * 4;
        f16x4 mx;
#pragma unroll
        for (int e = 0; e < 4; ++e) {
          mp[e] = M0v[e];
          mx[e] = (f16)(M0v[e] * (xv[e] * bA0[e] + bB0[e]));
        }
        *(f16x4*)(MxG + rg * 256 + l * 4) = mx;
      }
    } else if (s == 1) {
      att_phase<1>(P, tid, r0, wAtt, gatt + 256, batt + 256, x, P1, MxG, mkS, h, entAcc);
    } else {
      att_phase<2>(P, tid, r0, wAtt + 256 * 64, gatt + 512, batt + 512, x, P1, MxG, mkS, h, entAcc);
    }
    glu256_phase(P, tid, r0, wSh0, gsh0, bsh0, MxG, h0G);
    glu128_phase<0, 0>(P, tid, r0, s, wSh1, gsh1, bsh1, h0G, nullptr, h);
    glu128_phase<1, 0>(P, tid, r0, s, wSt + (size_t)(s * 2) * 256 * 128,
                       gstep + (s * 2) * 256, bstep + (s * 2) * 256, nullptr, nullptr, h);
    glu128_phase<1, 1>(P, tid, r0, s, wSt + (size_t)(s * 2 + 1) * 256 * 128,
                       gstep + (s * 2 + 1) * 256, bstep + (s * 2 + 1) * 256, nullptr, dout, h);
  }
#pragma unroll
  for (int d = 1; d < 64; d <<= 1) entAcc += __shfl_xor(entAcc, d);
  if (l == 0) sEnt[w] = entAcc;
  __syncthreads();
  if (tid == 0) {
    float t = 0.f;
#pragma unroll
    for (int i = 0; i < 16; ++i) t += sEnt[i];
    slpart[blockIdx.x] = t;
  }
}

__global__ void sl_final(const float* __restrict__ part, float* __restrict__ out) {
  __shared__ float sm[256];
  sm[threadIdx.x] = part[threadIdx.x];
  __syncthreads();
  for (int d = 128; d > 0; d >>= 1) {
    if ((int)threadIdx.x < d) sm[threadIdx.x] += sm[threadIdx.x + d];
    __syncthreads();
  }
  if (threadIdx.x == 0) out[0] = sm[0] * SL_SCALE;
}

// ---------------- host ----------------
extern "C" void kernel_launch(void* const* d_in, const int* in_sizes, int n_in,
                              void* d_out, int out_size, void* d_ws, size_t ws_size,
                              hipStream_t stream) {
  (void)in_sizes; (void)n_in; (void)out_size; (void)ws_size;
  const float* x    = (const float*)d_in[0];
  const float* bn0g = (const float*)d_in[1];
  const float* bn0b = (const float*)d_in[2];
  const float* Wsh0 = (const float*)d_in[3];
  const float* gsh0 = (const float*)d_in[4];
  const float* bsh0 = (const float*)d_in[5];
  const float* Wsh1 = (const float*)d_in[6];
  const float* gsh1 = (const float*)d_in[7];
  const float* bsh1 = (const float*)d_in[8];
  const float* Wstep = (const float*)d_in[9];
  const float* gstep = (const float*)d_in[10];
  const float* bstep = (const float*)d_in[11];
  const float* Watt = (const float*)d_in[12];
  const float* gatt = (const float*)d_in[13];
  const float* batt = (const float*)d_in[14];

  float* dout = (float*)d_out;
  float* slo = dout + (size_t)B_ROWS * 64;
  float* masks = slo + 1;

  char* ws = (char*)d_ws;
  size_t off = 0;
  auto carve = [&](size_t bytes) -> char* {
    char* p = ws + off;
    off += (bytes + 255) & ~(size_t)255;
    return p;
  };
  f16* wt_att   = (f16*)carve((size_t)2 * 256 * 64 * 2);
  f16* wt_sh0   = (f16*)carve((size_t)256 * 256 * 2);
  f16* wt_sh1   = (f16*)carve((size_t)256 * 128 * 2);
  f16* wt_step  = (f16*)carve((size_t)6 * 256 * 128 * 2);
  float* bn0sum = (float*)carve(512 * 4);
  float* bnA    = (float*)carve(256 * 4);
  float* bnB    = (float*)carve(256 * 4);
  float* slpart = (float*)carve(256 * 4);
  f16* P1       = (f16*)carve((size_t)B_ROWS * 256 * 2);
  f16* Mx       = (f16*)carve((size_t)B_ROWS * 256 * 2);
  f16* h0G      = (f16*)carve((size_t)B_ROWS * 128 * 2);

  hipMemsetAsync(bn0sum, 0, 512 * 4, stream);
  bn0_accum<<<2048, 256, 0, stream>>>(x, bn0sum);
  bn0_final<<<1, 256, 0, stream>>>(bn0sum, bn0g, bn0b, bnA, bnB);
  for (int s = 1; s < 3; ++s)
    wprep<<<64, 256, 0, stream>>>(Watt + (size_t)s * 64 * 256, wt_att + (size_t)(s - 1) * 256 * 64, 64);
  wprep<<<256, 256, 0, stream>>>(Wsh0, wt_sh0, 256);
  wprep<<<128, 256, 0, stream>>>(Wsh1, wt_sh1, 128);
  for (int i = 0; i < 6; ++i)
    wprep<<<128, 256, 0, stream>>>(Wstep + (size_t)i * 128 * 256, wt_step + (size_t)i * 256 * 128, 128);

  mega<<<256, 1024, 0, stream>>>(x, bnA, bnB, wt_att, wt_sh0, wt_sh1, wt_step,
                                 gsh0, bsh0, gsh1, bsh1, gstep, bstep, gatt, batt,
                                 P1, Mx, h0G, masks, dout, slpart);
  sl_final<<<1, 256, 0, stream>>>(slpart, slo);
}

// Round 8
// 1907.610 us; speedup vs baseline: 2.2683x; 2.2683x over previous
//
#include <hip/hip_runtime.h>
#include <math.h>

#define B_ROWS 262144
#define GAMMA_C 1.3f
#define EPS_C 1e-5f
#define SQH_C 0.70710678118654752440f
#define SL_SCALE (1.0f/201326592.0f)   // 1/(3*B*256)

typedef _Float16 f16;
typedef f16 f16x8 __attribute__((ext_vector_type(8)));
typedef f16 f16x4 __attribute__((ext_vector_type(4)));
typedef float f32x4 __attribute__((ext_vector_type(4)));

__device__ __forceinline__ int SWZ(int row, int kb, int RB, int MSK) {
  return row * RB + (kb ^ ((row & MSK) << 4));
}

// ---------------- bn0 ----------------
__global__ void bn0_accum(const float* __restrict__ x, float* __restrict__ sums) {
  const int col = threadIdx.x;
  const size_t r0 = (size_t)blockIdx.x * 128;
  float s1 = 0.f, s2 = 0.f;
  for (int i = 0; i < 128; ++i) {
    float v = x[(r0 + i) * 256 + col];
    s1 += v; s2 += v * v;
  }
  atomicAdd(&sums[col * 2], s1);
  atomicAdd(&sums[col * 2 + 1], s2);
}

__global__ void bn0_final(const float* __restrict__ sums, const float* __restrict__ g,
                          const float* __restrict__ b, float* __restrict__ bnA,
                          float* __restrict__ bnB) {
  int c = threadIdx.x;
  float mu = sums[c * 2] * (1.f / B_ROWS);
  float var = sums[c * 2 + 1] * (1.f / B_ROWS) - mu * mu;
  float a = rsqrtf(var + EPS_C) * g[c];
  bnA[c] = a;
  bnB[c] = b[c] - mu * a;
}

// ---------------- weight prep: f32 [K][256] -> f16 [256][K] ----------------
__global__ void wprep(const float* __restrict__ src, f16* __restrict__ dst, int K) {
  int idx = blockIdx.x * 256 + threadIdx.x;
  int n = idx / K, k = idx - n * K;
  dst[idx] = (f16)src[(size_t)k * 256 + n];
}

// ---------------- m0: step-0 mask row (identical for all rows) ----------------
__global__ void m0_kernel(const float* __restrict__ ba, float* __restrict__ m0v,
                          float* __restrict__ prior1v, float* __restrict__ slpart) {
  const int l = threadIdx.x;       // 64 threads
  const int c0 = l << 2;
  float z[4];
#pragma unroll
  for (int j = 0; j < 4; ++j) z[j] = ba[c0 + j];
  float m = fmaxf(fmaxf(z[0], z[1]), fmaxf(z[2], z[3]));
#pragma unroll
  for (int d = 1; d < 64; d <<= 1) m = fmaxf(m, __shfl_xor(m, d));
  float lo = m - 1.f, hi = m;
  for (int it = 0; it < 24; ++it) {
    float tau = 0.5f * (lo + hi);
    float s = fmaxf(z[0] - tau, 0.f) + fmaxf(z[1] - tau, 0.f) +
              fmaxf(z[2] - tau, 0.f) + fmaxf(z[3] - tau, 0.f);
#pragma unroll
    for (int d = 1; d < 64; d <<= 1) s += __shfl_xor(s, d);
    if (s > 1.f) lo = tau; else hi = tau;
  }
  const float tau = 0.5f * (lo + hi);
  float ent = 0.f;
#pragma unroll
  for (int j = 0; j < 4; ++j) {
    float M = fmaxf(z[j] - tau, 0.f);
    m0v[c0 + j] = M;
    prior1v[c0 + j] = GAMMA_C - M;
    ent -= M * __logf(M + 1e-15f);
  }
#pragma unroll
  for (int d = 1; d < 64; d <<= 1) ent += __shfl_xor(ent, d);
  if (l == 0) slpart[512] = ent * (262144.f * SL_SCALE);
}

// ---------------- step-0 masks broadcast + Mx = m0 * x_bn ----------------
__global__ void mx0_kernel(const float* __restrict__ x, const float* __restrict__ m0v,
                           const float* __restrict__ bnA, const float* __restrict__ bnB,
                           float* __restrict__ mk, f16* __restrict__ Mx) {
  __shared__ float sm[256], sa[256], sb[256];
  const int tid = threadIdx.x;
  sm[tid] = m0v[tid]; sa[tid] = bnA[tid]; sb[tid] = bnB[tid];
  __syncthreads();
  const size_t r = (size_t)blockIdx.x * 8 + (tid >> 5);
  const int c0 = (tid & 31) << 3;
  const float* xp = x + r * 256 + c0;
  f32x4 x0 = *(const f32x4*)xp;
  f32x4 x1 = *(const f32x4*)(xp + 4);
  float* mp = mk + r * 256 + c0;   // masks region only 4B-aligned: scalar stores
  f16x8 mxv;
#pragma unroll
  for (int j = 0; j < 4; ++j) {
    mp[j] = sm[c0 + j];
    mp[4 + j] = sm[c0 + 4 + j];
    mxv[j] = (f16)(sm[c0 + j] * (x0[j] * sa[c0 + j] + sb[c0 + j]));
    mxv[4 + j] = (f16)(sm[c0 + 4 + j] * (x1[j] * sa[c0 + 4 + j] + sb[c0 + 4 + j]));
  }
  *(f16x8*)(Mx + r * 256 + c0) = mxv;
}

// ---------------- fused two-pass GEMM + ghost-BN + GLU (one WG per VB) ----------------
// B-fragments in registers (wave owns GLU col pair {nw, nw+8}); A tile in LDS; no W in LDS.
template <int KD, int RESID, int DOUT>
__launch_bounds__(1024, 4)
__global__ void fglu(const f16* __restrict__ Ag, const f16* __restrict__ Wt,
                     const float* __restrict__ gv, const float* __restrict__ bv,
                     f16* __restrict__ ho, float* __restrict__ dout, int s) {
  constexpr int KS = KD / 32;
  constexpr int RB = KD * 2;
  constexpr int MSK = (RB / 16 - 1) < 31 ? (RB / 16 - 1) : 31;
  constexpr int SPT = (KD == 256) ? 2 : 1;    // f16x8 staging stores per thread
  constexpr int TPR = KD / 8;                 // staging threads per row
  __shared__ __align__(16) f16 sA[64 * KD];
  __shared__ float sS1[512], sS2[512], sAf[256], sBf[256];
  char* sAc = (char*)sA;
  const int tid = threadIdx.x;
  const int w = tid >> 6, l = tid & 63, lg = l >> 4, lc = l & 15;
  const int mw = w >> 3, nw = w & 7;
  const int c1 = nw * 16 + lc, c2 = c1 + 128;
  const int r0 = blockIdx.x << 10;

  // hoist W fragments (col pair) into registers — reused by both passes
  f16x8 bf0[KS], bf1[KS];
#pragma unroll
  for (int ks = 0; ks < KS; ++ks) {
    bf0[ks] = *(const f16x8*)(Wt + (size_t)c1 * KD + ks * 32 + lg * 8);
    bf1[ks] = *(const f16x8*)(Wt + (size_t)c2 * KD + ks * 32 + lg * 8);
  }

  f16x8 pv[SPT];
  auto LDA = [&](int ch) {
#pragma unroll
    for (int p = 0; p < SPT; ++p) {
      int flat = p * 1024 + tid;
      int row = flat / TPR, kc = flat % TPR;
      pv[p] = *(const f16x8*)(Ag + (size_t)(r0 + ch * 64 + row) * KD + kc * 8);
    }
  };
  auto STA = [&]() {
#pragma unroll
    for (int p = 0; p < SPT; ++p) {
      int flat = p * 1024 + tid;
      int row = flat / TPR, kc = flat % TPR;
      *(f16x8*)(sAc + SWZ(row, kc * 16, RB, MSK)) = pv[p];
    }
  };

  // ---------------- pass 0: stats ----------------
  float st1a = 0.f, st2a = 0.f, st1b = 0.f, st2b = 0.f;
  LDA(0);
  for (int ch = 0; ch < 16; ++ch) {
    __syncthreads();
    STA();
    __syncthreads();
    if (ch < 15) LDA(ch + 1);
#pragma unroll
    for (int mt = 0; mt < 2; ++mt) {
      f32x4 a0 = {0.f,0.f,0.f,0.f}, a1 = {0.f,0.f,0.f,0.f};
      const int ar = mw * 32 + mt * 16 + lc;
#pragma unroll
      for (int ks = 0; ks < KS; ++ks) {
        f16x8 af = *(const f16x8*)(sAc + SWZ(ar, ks * 64 + lg * 16, RB, MSK));
        a0 = __builtin_amdgcn_mfma_f32_16x16x32_f16(af, bf0[ks], a0, 0, 0, 0);
        a1 = __builtin_amdgcn_mfma_f32_16x16x32_f16(af, bf1[ks], a1, 0, 0, 0);
      }
#pragma unroll
      for (int j = 0; j < 4; ++j) {
        st1a += a0[j]; st2a += a0[j] * a0[j];
        st1b += a1[j]; st2b += a1[j] * a1[j];
      }
    }
  }
  st1a += __shfl_xor(st1a, 16); st1a += __shfl_xor(st1a, 32);
  st2a += __shfl_xor(st2a, 16); st2a += __shfl_xor(st2a, 32);
  st1b += __shfl_xor(st1b, 16); st1b += __shfl_xor(st1b, 32);
  st2b += __shfl_xor(st2b, 16); st2b += __shfl_xor(st2b, 32);
  if (l < 16) {
    sS1[mw * 256 + c1] = st1a; sS2[mw * 256 + c1] = st2a;
    sS1[mw * 256 + c2] = st1b; sS2[mw * 256 + c2] = st2b;
  }
  __syncthreads();
  if (tid < 256) {
    float s1 = sS1[tid] + sS1[256 + tid];
    float s2 = sS2[tid] + sS2[256 + tid];
    float mu = s1 * (1.f / 1024.f);
    float var = s2 * (1.f / 1024.f) - mu * mu;
    float a = rsqrtf(var + EPS_C) * gv[tid];
    sAf[tid] = a; sBf[tid] = bv[tid] - mu * a;
  }
  __syncthreads();
  const float bA1 = sAf[c1], bO1 = sBf[c1], bA2 = sAf[c2], bO2 = sBf[c2];

  // ---------------- pass 1: apply (residual + dout in f32 at MFMA side) ----------------
  LDA(0);
  for (int ch = 0; ch < 16; ++ch) {
    __syncthreads();
    STA();
    __syncthreads();
    if (ch < 15) LDA(ch + 1);
#pragma unroll
    for (int mt = 0; mt < 2; ++mt) {
      f32x4 a0 = {0.f,0.f,0.f,0.f}, a1 = {0.f,0.f,0.f,0.f};
      const int ar = mw * 32 + mt * 16 + lc;
#pragma unroll
      for (int ks = 0; ks < KS; ++ks) {
        f16x8 af = *(const f16x8*)(sAc + SWZ(ar, ks * 64 + lg * 16, RB, MSK));
        a0 = __builtin_amdgcn_mfma_f32_16x16x32_f16(af, bf0[ks], a0, 0, 0, 0);
        a1 = __builtin_amdgcn_mfma_f32_16x16x32_f16(af, bf1[ks], a1, 0, 0, 0);
      }
#pragma unroll
      for (int j = 0; j < 4; ++j) {
        float g1 = a0[j] * bA1 + bO1;
        float g2 = a1[j] * bA2 + bO2;
        float hv = g1 / (1.f + __expf(-g2));
        const int rl = mw * 32 + mt * 16 + lg * 4 + j;
        if (RESID) {
          f16 hp = *(const f16*)(sAc + SWZ(rl, c1 * 2, RB, MSK));  // A-tile IS h_prev
          hv = (hv + (float)hp) * SQH_C;
        }
        if (DOUT && nw < 4) {          // c1 < 64, wave-uniform branch
          float rv = fmaxf(hv, 0.f);
          float* dp = dout + (size_t)(r0 + ch * 64 + rl) * 64 + c1;
          if (s == 0) *dp = rv; else *dp += rv;
        }
        ho[(size_t)(r0 + ch * 64 + rl) * 128 + c1] = (f16)hv;
      }
    }
  }
}

// ---------------- fused attention GEMM + ghost-BN + sparsemax + mask products ----------------
// SMODE 1: prior = broadcast vector, writes prior buffer. SMODE 2: prior = buffer, no write.
template <int SMODE>
__launch_bounds__(512)
__global__ void attmask(const f16* __restrict__ h1, const f16* __restrict__ Wt,
                        const float* __restrict__ ga, const float* __restrict__ ba,
                        const float* __restrict__ bnA, const float* __restrict__ bnB,
                        const float* __restrict__ prior1v, const f16* __restrict__ prin,
                        f16* __restrict__ prout, const float* __restrict__ x,
                        float* __restrict__ mk, f16* __restrict__ Mx,
                        float* __restrict__ slpart) {
  __shared__ f16 sW[256 * 64];
  __shared__ f16 sA[128 * 64];
  __shared__ float sS1[256], sS2[256], sAf[256], sBf[256], sbA[256], sbB[256], spv[256];
  __shared__ float sEnt[8];
  char* sWc = (char*)sW;
  char* sAc = (char*)sA;
  const int tid = threadIdx.x;
  const int vb = blockIdx.x;
  const int r0 = vb << 10;
  const int w = tid >> 6, l = tid & 63, lc = l & 15, lg = l >> 4;
  if (tid < 256) {
    sS1[tid] = 0.f; sS2[tid] = 0.f;
    sbA[tid] = bnA[tid]; sbB[tid] = bnB[tid];
    if (SMODE == 1) spv[tid] = prior1v[tid];
  }
#pragma unroll
  for (int it = 0; it < 4; ++it) {
    int flat = it * 512 + tid;
    int rw = flat >> 3, kc = flat & 7;
    *(f16x8*)(sWc + SWZ(rw, kc * 16, 128, 7)) = *(const f16x8*)(Wt + rw * 64 + kc * 8);
  }
  const int arow = tid >> 3, akc = tid & 7;
  const f16* aB = h1 + (size_t)(r0 + arow) * 128 + 64 + akc * 8;
  float ent = 0.f;

  for (int pass = 0; pass < 2; ++pass) {
    float st1[16], st2[16];
#pragma unroll
    for (int t = 0; t < 16; ++t) { st1[t] = 0.f; st2[t] = 0.f; }
    f16x8 pv0 = *(const f16x8*)(aB);
    f16x8 pv1 = *(const f16x8*)(aB + (size_t)64 * 128);
    for (int ch = 0; ch < 8; ++ch) {
      __syncthreads();
      *(f16x8*)(sAc + SWZ(arow, akc * 16, 128, 7)) = pv0;
      *(f16x8*)(sAc + SWZ(arow + 64, akc * 16, 128, 7)) = pv1;
      __syncthreads();
      if (ch + 1 < 8) {
        pv0 = *(const f16x8*)(aB + (size_t)(ch + 1) * 128 * 128);
        pv1 = *(const f16x8*)(aB + (size_t)((ch + 1) * 128 + 64) * 128);
      }
      f16x8 af0 = *(const f16x8*)(sAc + SWZ(w * 16 + lc, lg * 16, 128, 7));
      f16x8 af1 = *(const f16x8*)(sAc + SWZ(w * 16 + lc, 64 + lg * 16, 128, 7));
      const int rb = r0 + ch * 128 + w * 16;
      f32x4 z[16];
#pragma unroll
      for (int t = 0; t < 16; ++t) {
        f16x8 b0 = *(const f16x8*)(sWc + SWZ(t * 16 + lc, lg * 16, 128, 7));
        f16x8 b1 = *(const f16x8*)(sWc + SWZ(t * 16 + lc, 64 + lg * 16, 128, 7));
        f32x4 acc = {0.f, 0.f, 0.f, 0.f};
        acc = __builtin_amdgcn_mfma_f32_16x16x32_f16(af0, b0, acc, 0, 0, 0);
        acc = __builtin_amdgcn_mfma_f32_16x16x32_f16(af1, b1, acc, 0, 0, 0);
        if (pass == 0) {
          float s1 = 0.f, s2 = 0.f;
#pragma unroll
          for (int j = 0; j < 4; ++j) { float v = acc[j]; s1 += v; s2 += v * v; }
          st1[t] += s1; st2[t] += s2;
        } else {
          const int c = t * 16 + lc;
          const float a = sAf[c], bb = sBf[c];
#pragma unroll
          for (int j = 0; j < 4; ++j) {
            float pr;
            if (SMODE == 1) pr = spv[c];
            else pr = (float)prin[(size_t)(rb + lg * 4 + j) * 256 + c];
            z[t][j] = (acc[j] * a + bb) * pr;
          }
        }
      }
      if (pass == 1) {
        // in-register sparsemax for rows rb + lg*4 + {0..3}
        f32x4 mj, lo, hi;
#pragma unroll
        for (int j = 0; j < 4; ++j) {
          float m = z[0][j];
#pragma unroll
          for (int t = 1; t < 16; ++t) m = fmaxf(m, z[t][j]);
          mj[j] = m;
        }
#pragma unroll
        for (int d = 1; d < 16; d <<= 1)
#pragma unroll
          for (int j = 0; j < 4; ++j) mj[j] = fmaxf(mj[j], __shfl_xor(mj[j], d));
#pragma unroll
        for (int j = 0; j < 4; ++j) { lo[j] = mj[j] - 1.f; hi[j] = mj[j]; }
        for (int itb = 0; itb < 20; ++itb) {
          f32x4 tau, sv;
#pragma unroll
          for (int j = 0; j < 4; ++j) { tau[j] = 0.5f * (lo[j] + hi[j]); sv[j] = 0.f; }
#pragma unroll
          for (int t = 0; t < 16; ++t)
#pragma unroll
            for (int j = 0; j < 4; ++j) sv[j] += fmaxf(z[t][j] - tau[j], 0.f);
#pragma unroll
          for (int d = 1; d < 16; d <<= 1)
#pragma unroll
            for (int j = 0; j < 4; ++j) sv[j] += __shfl_xor(sv[j], d);
#pragma unroll
          for (int j = 0; j < 4; ++j) { if (sv[j] > 1.f) lo[j] = tau[j]; else hi[j] = tau[j]; }
        }
        f32x4 tau;
#pragma unroll
        for (int j = 0; j < 4; ++j) tau[j] = 0.5f * (lo[j] + hi[j]);
#pragma unroll
        for (int t = 0; t < 16; ++t) {
          const int c = t * 16 + lc;
#pragma unroll
          for (int j = 0; j < 4; ++j) {
            const size_t r = (size_t)(rb + lg * 4 + j);
            float Mv = fmaxf(z[t][j] - tau[j], 0.f);
            mk[r * 256 + c] = Mv;
            ent -= Mv * __logf(Mv + 1e-15f);
            float xb = x[r * 256 + c] * sbA[c] + sbB[c];
            Mx[r * 256 + c] = (f16)(Mv * xb);
            if (SMODE == 1) prout[r * 256 + c] = (f16)(spv[c] * (GAMMA_C - Mv));
          }
        }
      }
    }
    if (pass == 0) {
#pragma unroll
      for (int t = 0; t < 16; ++t) {
        float v1 = st1[t], v2 = st2[t];
        v1 += __shfl_xor(v1, 16); v2 += __shfl_xor(v2, 16);
        v1 += __shfl_xor(v1, 32); v2 += __shfl_xor(v2, 32);
        if (l < 16) {
          atomicAdd(&sS1[t * 16 + lc], v1);
          atomicAdd(&sS2[t * 16 + lc], v2);
        }
      }
      __syncthreads();
      if (tid < 256) {
        float mu = sS1[tid] * (1.f / 1024.f);
        float var = sS2[tid] * (1.f / 1024.f) - mu * mu;
        float a = rsqrtf(var + EPS_C) * ga[tid];
        sAf[tid] = a;
        sBf[tid] = ba[tid] - mu * a;
      }
      __syncthreads();
    }
  }
#pragma unroll
  for (int d = 1; d < 64; d <<= 1) ent += __shfl_xor(ent, d);
  if (l == 0) sEnt[w] = ent;
  __syncthreads();
  if (tid == 0) {
    float t = 0.f;
#pragma unroll
    for (int i = 0; i < 8; ++i) t += sEnt[i];
    slpart[(SMODE - 1) * 256 + vb] = t * SL_SCALE;
  }
}

__global__ void sl_reduce(const float* __restrict__ part, float* __restrict__ out, int n) {
  __shared__ float sm[256];
  float s = 0.f;
  for (int i = threadIdx.x; i < n; i += 256) s += part[i];
  sm[threadIdx.x] = s;
  __syncthreads();
  for (int d = 128; d > 0; d >>= 1) {
    if ((int)threadIdx.x < d) sm[threadIdx.x] += sm[threadIdx.x + d];
    __syncthreads();
  }
  if (threadIdx.x == 0) out[0] = sm[0];
}

// ---------------- host ----------------
extern "C" void kernel_launch(void* const* d_in, const int* in_sizes, int n_in,
                              void* d_out, int out_size, void* d_ws, size_t ws_size,
                              hipStream_t stream) {
  (void)in_sizes; (void)n_in; (void)out_size; (void)ws_size;
  const float* x    = (const float*)d_in[0];
  const float* bn0g = (const float*)d_in[1];
  const float* bn0b = (const float*)d_in[2];
  const float* Wsh0 = (const float*)d_in[3];
  const float* gsh0 = (const float*)d_in[4];
  const float* bsh0 = (const float*)d_in[5];
  const float* Wsh1 = (const float*)d_in[6];
  const float* gsh1 = (const float*)d_in[7];
  const float* bsh1 = (const float*)d_in[8];
  const float* Wstep = (const float*)d_in[9];
  const float* gstep = (const float*)d_in[10];
  const float* bstep = (const float*)d_in[11];
  const float* Watt = (const float*)d_in[12];
  const float* gatt = (const float*)d_in[13];
  const float* batt = (const float*)d_in[14];

  float* dout = (float*)d_out;
  float* slo = dout + (size_t)B_ROWS * 64;
  float* masks = slo + 1;

  char* ws = (char*)d_ws;
  size_t off = 0;
  auto carve = [&](size_t bytes) -> char* {
    char* p = ws + off;
    off += (bytes + 255) & ~(size_t)255;
    return p;
  };
  f16* wt_att   = (f16*)carve((size_t)3 * 256 * 64 * 2);
  f16* wt_sh0   = (f16*)carve((size_t)256 * 256 * 2);
  f16* wt_sh1   = (f16*)carve((size_t)256 * 128 * 2);
  f16* wt_step  = (f16*)carve((size_t)6 * 256 * 128 * 2);
  float* bn0sum = (float*)carve(512 * 4);
  float* bnA    = (float*)carve(256 * 4);
  float* bnB    = (float*)carve(256 * 4);
  float* m0v    = (float*)carve(256 * 4);
  float* prior1v= (float*)carve(256 * 4);
  float* slpart = (float*)carve(513 * 4);
  f16* prior    = (f16*)carve((size_t)B_ROWS * 256 * 2);
  f16* Mx       = (f16*)carve((size_t)B_ROWS * 256 * 2);
  f16* h0       = (f16*)carve((size_t)B_ROWS * 128 * 2);
  f16* h1       = (f16*)carve((size_t)B_ROWS * 128 * 2);

  // prep
  hipMemsetAsync(bn0sum, 0, 512 * 4, stream);
  bn0_accum<<<2048, 256, 0, stream>>>(x, bn0sum);
  bn0_final<<<1, 256, 0, stream>>>(bn0sum, bn0g, bn0b, bnA, bnB);
  for (int s = 1; s < 3; ++s)
    wprep<<<64, 256, 0, stream>>>(Watt + (size_t)s * 64 * 256, wt_att + (size_t)s * 256 * 64, 64);
  wprep<<<256, 256, 0, stream>>>(Wsh0, wt_sh0, 256);
  wprep<<<128, 256, 0, stream>>>(Wsh1, wt_sh1, 128);
  for (int i = 0; i < 6; ++i)
    wprep<<<128, 256, 0, stream>>>(Wstep + (size_t)i * 128 * 256, wt_step + (size_t)i * 256 * 128, 128);
  m0_kernel<<<1, 64, 0, stream>>>(batt, m0v, prior1v, slpart);
  mx0_kernel<<<B_ROWS / 8, 256, 0, stream>>>(x, m0v, bnA, bnB, masks, Mx);

  for (int s = 0; s < 3; ++s) {
    if (s == 1)
      attmask<1><<<256, 512, 0, stream>>>(h1, wt_att + (size_t)1 * 256 * 64,
                                          gatt + 256, batt + 256, bnA, bnB,
                                          prior1v, nullptr, prior, x,
                                          masks + (size_t)1 * B_ROWS * 256, Mx, slpart);
    else if (s == 2)
      attmask<2><<<256, 512, 0, stream>>>(h1, wt_att + (size_t)2 * 256 * 64,
                                          gatt + 512, batt + 512, bnA, bnB,
                                          nullptr, prior, nullptr, x,
                                          masks + (size_t)2 * B_ROWS * 256, Mx, slpart);
    fglu<256, 0, 0><<<256, 1024, 0, stream>>>(Mx, wt_sh0, gsh0, bsh0, h0, nullptr, s);
    fglu<128, 1, 0><<<256, 1024, 0, stream>>>(h0, wt_sh1, gsh1, bsh1, h1, nullptr, s);
    fglu<128, 1, 0><<<256, 1024, 0, stream>>>(h1, wt_step + (size_t)(s * 2 + 0) * 256 * 128,
                                              gstep + (s * 2 + 0) * 256, bstep + (s * 2 + 0) * 256,
                                              h0, nullptr, s);
    fglu<128, 1, 1><<<256, 1024, 0, stream>>>(h0, wt_step + (size_t)(s * 2 + 1) * 256 * 128,
                                              gstep + (s * 2 + 1) * 256, bstep + (s * 2 + 1) * 256,
                                              h1, dout, s);
  }
  sl_reduce<<<1, 256, 0, stream>>>(slpart, slo, 513);
}